// Round 5
// baseline (3520.745 us; speedup 1.0000x reference)
//
#include <hip/hip_runtime.h>
#include <hip/hip_bf16.h>
#include <hip/hip_fp16.h>

#define BT 16384
#define F 32
#define H 256
#define FH 8192

typedef _Float16 half8 __attribute__((ext_vector_type(8)));
typedef float float4v __attribute__((ext_vector_type(4)));

#define GLD_LDS(gsrc, ldst) \
    __builtin_amdgcn_global_load_lds( \
        (const __attribute__((address_space(1))) void*)(gsrc), \
        (__attribute__((address_space(3))) void*)(ldst), 16, 0, 0)

// ---------------------------------------------------------------------------
// Prep: transpose w2/wg/wf (F,H_contr,H_out) fp32 -> [f][n_out][h_contr] fp16
// ---------------------------------------------------------------------------
__global__ __launch_bounds__(256) void transpose_w_kernel(
    const float* __restrict__ w2, const float* __restrict__ wg,
    const float* __restrict__ wf, _Float16* __restrict__ wt)
{
    __shared__ float tile[64][65];
    int bid = blockIdx.x;
    int tens = bid >> 9, rem = bid & 511;
    int f = rem >> 4, tl = rem & 15;
    int hb = (tl >> 2) * 64, nb = (tl & 3) * 64;
    const float* src = (tens == 0 ? w2 : (tens == 1 ? wg : wf)) + f * 65536;
    _Float16* dst = wt + (size_t)tens * 2097152 + f * 65536;
    int lane = threadIdx.x & 63, w = threadIdx.x >> 6;
    for (int i = 0; i < 16; ++i) {
        int r = i * 4 + w;
        tile[r][lane] = src[(hb + r) * 256 + nb + lane];
    }
    __syncthreads();
    for (int i = 0; i < 16; ++i) {
        int c = i * 4 + w;
        dst[(nb + c) * 256 + hb + lane] = (_Float16)tile[lane][c];
    }
}

// ---------------------------------------------------------------------------
// Prep: wcat[n][k] fp16 (n<256 sw1-T, n 256..287 ssw-T) + sw2t[n][k] fp16
// ---------------------------------------------------------------------------
__global__ __launch_bounds__(256) void transpose_s_kernel(
    const float* __restrict__ sw1, const float* __restrict__ ssw,
    const float* __restrict__ sw2, _Float16* __restrict__ wcat,
    _Float16* __restrict__ sw2t)
{
    __shared__ float tile[64][65];
    int bid = blockIdx.x;
    int lane = threadIdx.x & 63, w = threadIdx.x >> 6;
    int t = threadIdx.x;
    if (bid < 512) {
        int k0 = (bid >> 2) * 64, n0 = (bid & 3) * 64;
        for (int i = 0; i < 16; ++i) {
            int r = i * 4 + w;
            tile[r][lane] = sw1[(size_t)(k0 + r) * 256 + n0 + lane];
        }
        __syncthreads();
        for (int i = 0; i < 16; ++i) {
            int c = i * 4 + w;
            wcat[(size_t)(n0 + c) * FH + k0 + lane] = (_Float16)tile[lane][c];
        }
    } else if (bid < 640) {
        int k0 = (bid - 512) * 64;
        for (int i = 0; i < 8; ++i) {
            int idx = t + i * 256;
            int r = idx >> 5, cc = idx & 31;
            tile[r][cc] = ssw[(size_t)(k0 + r) * 32 + cc];
        }
        __syncthreads();
        for (int i = 0; i < 8; ++i) {
            int idx = t + i * 256;
            int c = idx >> 6, rr = idx & 63;
            wcat[(size_t)(256 + c) * FH + k0 + rr] = (_Float16)tile[rr][c];
        }
    } else {
        // sw2 (256,32) -> sw2t[n*256+k]
        for (int i = 0; i < 32; ++i) {
            int idx = t + i * 256;
            int k = idx >> 5, n = idx & 31;
            sw2t[n * 256 + k] = (_Float16)sw2[idx];
        }
    }
}

// ---------------------------------------------------------------------------
// GRN gemm stage: global_load_lds + XOR swizzle (verified R3/R4).
// Bs row n, chunk-pos cp holds source chunk cp^(n&7).
// ---------------------------------------------------------------------------
__device__ __forceinline__ void gemm_stage(
    const _Float16* __restrict__ Bsrc,   // [n][k] for this f, k contig (256x256)
    const _Float16* As, _Float16* Bs,
    int t, int wv, int ln, int q, float4v acc[2][4])
{
    for (int kc = 0; kc < 4; ++kc) {
        __syncthreads();
#pragma unroll
        for (int it = 0; it < 8; ++it) {
            int s = it * 256 + t;
            int n = s >> 3;
            int c = (s & 7) ^ (n & 7);
            GLD_LDS(Bsrc + n * 256 + kc * 64 + c * 8, Bs + s * 8);
        }
        __syncthreads();
        for (int ks = 0; ks < 2; ++ks) {
            int kb = kc * 64 + ks * 32 + q * 8;
            half8 a0 = *(const half8*)&As[(0 + ln) * 264 + kb];
            half8 a1 = *(const half8*)&As[(16 + ln) * 264 + kb];
#pragma unroll
            for (int nt = 0; nt < 4; ++nt) {
                int n = wv * 64 + nt * 16 + ln;
                int cp = (ks * 4 + q) ^ (n & 7);
                half8 b8 = *(const half8*)&Bs[n * 64 + cp * 8];
                acc[0][nt] = __builtin_amdgcn_mfma_f32_16x16x32_f16(a0, b8, acc[0][nt], 0, 0, 0);
                acc[1][nt] = __builtin_amdgcn_mfma_f32_16x16x32_f16(a1, b8, acc[1][nt], 0, 0, 0);
            }
        }
    }
}

// ---------------------------------------------------------------------------
// GRN core: given f, compute stacked_f values into yv (C-layout regs),
// normalized by in-register LayerNorm (shuffle + tiny red/mv LDS).
// On return, yv[mt][nt][r] = stacked[m][n] for m=mt*16+q*4+r, n=wv*64+nt*16+ln.
// ---------------------------------------------------------------------------
__device__ __forceinline__ void grn_core(
    int f, const float* __restrict__ w1, const float* __restrict__ b1,
    const float* __restrict__ b2, const float* __restrict__ bg,
    const float* __restrict__ bfv_, const float* __restrict__ gamma,
    const float* __restrict__ beta, const float* __restrict__ wsk,
    const float* __restrict__ bsk,
    const _Float16* __restrict__ w2t, const _Float16* __restrict__ wgt,
    const _Float16* __restrict__ wft,
    _Float16* As, _Float16* Bs, const float* xs_t, float* red, float* mv,
    int t, int wv, int ln, int q, float yv[2][4][4])
{
    __syncthreads();   // protect As from prior readers
    {
        float w1v = w1[f * H + t];
        float b1v = b1[f * H + t];
#pragma unroll 4
        for (int i = 0; i < 32; ++i) {
            float z = xs_t[f * 32 + i] * w1v + b1v;
            float e = z > 0.f ? z : (expf(z) - 1.f);
            As[i * 264 + t] = (_Float16)e;
        }
    }
    float4v acc1[2][4];
#pragma unroll
    for (int mt = 0; mt < 2; ++mt)
#pragma unroll
        for (int nt = 0; nt < 4; ++nt)
#pragma unroll
            for (int r = 0; r < 4; ++r) acc1[mt][nt][r] = 0.f;
    gemm_stage(w2t + (size_t)f * 65536, As, Bs, t, wv, ln, q, acc1);
    __syncthreads();
    {
        const float* b2f = b2 + f * H;
#pragma unroll
        for (int mt = 0; mt < 2; ++mt)
#pragma unroll
            for (int nt = 0; nt < 4; ++nt) {
                int n = wv * 64 + nt * 16 + ln;
                float b2v = b2f[n];
#pragma unroll
                for (int r = 0; r < 4; ++r) {
                    int m = mt * 16 + q * 4 + r;
                    As[m * 264 + n] = (_Float16)(acc1[mt][nt][r] + b2v);
                }
            }
    }
    float4v accG[2][4], accF[2][4];
#pragma unroll
    for (int mt = 0; mt < 2; ++mt)
#pragma unroll
        for (int nt = 0; nt < 4; ++nt)
#pragma unroll
            for (int r = 0; r < 4; ++r) { accG[mt][nt][r] = 0.f; accF[mt][nt][r] = 0.f; }
    gemm_stage(wgt + (size_t)f * 65536, As, Bs, t, wv, ln, q, accG);
    gemm_stage(wft + (size_t)f * 65536, As, Bs, t, wv, ln, q, accF);
    __syncthreads();   // all GEMM2 MFMA done (As/Bs free); red safe to write
    // GLU + residual (in registers)
    {
        const float* bgf = bg + f * H;
        const float* bff = bfv_ + f * H;
        const float* wsf = wsk + f * H;
        const float* bsf = bsk + f * H;
#pragma unroll
        for (int mt = 0; mt < 2; ++mt)
#pragma unroll
            for (int nt = 0; nt < 4; ++nt) {
                int n = wv * 64 + nt * 16 + ln;
                float bgv = bgf[n], bfv = bff[n], wsv = wsf[n], bsv = bsf[n];
#pragma unroll
                for (int r = 0; r < 4; ++r) {
                    int m = mt * 16 + q * 4 + r;
                    float cg = accG[mt][nt][r] + bgv;
                    float cf = accF[mt][nt][r] + bfv;
                    float sig = 1.f / (1.f + expf(-cg));
                    yv[mt][nt][r] = sig * cf + xs_t[f * 32 + m] * wsv + bsv;
                }
            }
    }
    // in-register LayerNorm: row sums via 16-lane butterfly
#pragma unroll
    for (int mt = 0; mt < 2; ++mt)
#pragma unroll
        for (int r = 0; r < 4; ++r) {
            float s1 = 0.f, s2 = 0.f;
#pragma unroll
            for (int nt = 0; nt < 4; ++nt) {
                float v = yv[mt][nt][r];
                s1 += v; s2 += v * v;
            }
#pragma unroll
            for (int off = 1; off < 16; off <<= 1) {
                s1 += __shfl_xor(s1, off, 16);
                s2 += __shfl_xor(s2, off, 16);
            }
            if (ln == 0) {
                int m = mt * 16 + q * 4 + r;
                red[m * 4 + wv] = s1;
                red[128 + m * 4 + wv] = s2;
            }
        }
    __syncthreads();
    if (t < 32) {
        float a = red[t * 4] + red[t * 4 + 1] + red[t * 4 + 2] + red[t * 4 + 3];
        float b = red[128 + t * 4] + red[128 + t * 4 + 1] + red[128 + t * 4 + 2] + red[128 + t * 4 + 3];
        float mean = a * (1.f / 256.f);
        float var = b * (1.f / 256.f) - mean * mean;
        mv[t] = mean;
        mv[32 + t] = rsqrtf(var + 1e-5f);
    }
    __syncthreads();
    {
        const float* gf = gamma + f * H;
        const float* bf2 = beta + f * H;
#pragma unroll
        for (int mt = 0; mt < 2; ++mt)
#pragma unroll
            for (int nt = 0; nt < 4; ++nt) {
                int n = wv * 64 + nt * 16 + ln;
                float gv = gf[n], bv = bf2[n];
#pragma unroll
                for (int r = 0; r < 4; ++r) {
                    int m = mt * 16 + q * 4 + r;
                    yv[mt][nt][r] = (yv[mt][nt][r] - mv[m]) * mv[32 + m] * gv + bv;
                }
            }
    }
}

// ---------------------------------------------------------------------------
// PASS 1: per 32-token tile, loop f: grn_core -> stacked_f -> As ->
// accumulate sel GEMM (32x288, K=256 per f). Then fused selection tail
// (fc2 MFMA, GLU, LN, softmax) -> write w[token][32].
// ---------------------------------------------------------------------------
__global__ __launch_bounds__(256) void pass1_kernel(
    const float* __restrict__ x, const float* __restrict__ w1, const float* __restrict__ b1,
    const float* __restrict__ b2, const float* __restrict__ bg, const float* __restrict__ bfv_,
    const float* __restrict__ gamma, const float* __restrict__ beta,
    const float* __restrict__ wsk, const float* __restrict__ bsk,
    const _Float16* __restrict__ w2t, const _Float16* __restrict__ wgt,
    const _Float16* __restrict__ wft, const _Float16* __restrict__ wcat,
    const _Float16* __restrict__ sw2t,
    const float* __restrict__ sb1, const float* __restrict__ ssb,
    const float* __restrict__ sb2, const float* __restrict__ swg,
    const float* __restrict__ sbg, const float* __restrict__ swf,
    const float* __restrict__ sbf, const float* __restrict__ sgam,
    const float* __restrict__ sbet, float* __restrict__ wout)
{
    __shared__ __align__(16) char smem[59136];
    _Float16* As = (_Float16*)smem;                    // 32x264 fp16 [0,16896)
    _Float16* Bs = (_Float16*)(smem + 16896);          // 288x64 fp16 [16896,53760)
    float* xs_t  = (float*)(smem + 53760);             // [f][m] 32x32 [53760,57856)
    float* red   = (float*)(smem + 57856);             // 256 f32
    float* mv    = (float*)(smem + 58880);             // 64 f32
    // tail aliases (As/Bs dead at tail):
    _Float16* ys16  = (_Float16*)smem;                 // 32x264 fp16
    _Float16* sw2s  = (_Float16*)(smem + 16896);       // 32x256 fp16 [.. 33280)
    float* sres_t   = (float*)(smem + 33280);          // [j][m] 32x32 [.. 37376)
    float* tv_t     = (float*)(smem + 37376);          // [j][m] 32x32 [.. 41472)
    float* w_lds    = (float*)(smem + 41472);          // [m][j] 32x32 [.. 45568)

    const int m0 = blockIdx.x * 32;
    const int t = threadIdx.x;
    const int wv = t >> 6, ln = t & 15, q = (t & 63) >> 4;
    const int NT = (wv < 2) ? 5 : 4;

    // stage x tile transposed: xs_t[f*32+m]
#pragma unroll
    for (int i = 0; i < 4; ++i) {
        int idx = t + i * 256;
        xs_t[(idx & 31) * 32 + (idx >> 5)] = x[(size_t)m0 * F + idx];
    }

    float4v selacc[2][5];
#pragma unroll
    for (int mt = 0; mt < 2; ++mt)
#pragma unroll
        for (int i = 0; i < 5; ++i)
#pragma unroll
            for (int r = 0; r < 4; ++r) selacc[mt][i][r] = 0.f;
    __syncthreads();

    float yv[2][4][4];
    for (int f = 0; f < F; ++f) {
        grn_core(f, w1, b1, b2, bg, bfv_, gamma, beta, wsk, bsk,
                 w2t, wgt, wft, As, Bs, xs_t, red, mv, t, wv, ln, q, yv);
        // write stacked_f (fp16) into As (A-layout, k_local = n)
#pragma unroll
        for (int mt = 0; mt < 2; ++mt)
#pragma unroll
            for (int nt = 0; nt < 4; ++nt) {
                int n = wv * 64 + nt * 16 + ln;
#pragma unroll
                for (int r = 0; r < 4; ++r) {
                    int m = mt * 16 + q * 4 + r;
                    As[m * 264 + n] = (_Float16)yv[mt][nt][r];
                }
            }
        __syncthreads();
        // selection GEMM accumulate over this f's 256-k slice
        for (int kc = 0; kc < 4; ++kc) {
            if (kc) __syncthreads();
#pragma unroll
            for (int i = 0; i < 9; ++i) {
                int s = t + i * 256;
                int nb = s >> 3;
                int cb = (s & 7) ^ (nb & 7);
                GLD_LDS(wcat + (size_t)nb * FH + f * 256 + kc * 64 + cb * 8, Bs + s * 8);
            }
            __syncthreads();
            for (int ks = 0; ks < 2; ++ks) {
                half8 af[2];
#pragma unroll
                for (int mt = 0; mt < 2; ++mt)
                    af[mt] = *(const half8*)&As[(mt * 16 + ln) * 264 + kc * 64 + ks * 32 + q * 8];
                for (int i = 0; i < NT; ++i) {
                    int row = (wv + 4 * i) * 16 + ln;
                    int cp = (ks * 4 + q) ^ (row & 7);
                    half8 b8 = *(const half8*)&Bs[row * 64 + cp * 8];
#pragma unroll
                    for (int mt = 0; mt < 2; ++mt)
                        selacc[mt][i] = __builtin_amdgcn_mfma_f32_16x16x32_f16(af[mt], b8, selacc[mt][i], 0, 0, 0);
                }
            }
        }
    }

    // ------------------- selection tail -------------------
    __syncthreads();   // sel MFMAs done reading As/Bs
    // stage elu(fc1+sb1) fp16 (A-layout) and sres (fp32)
    for (int i = 0; i < NT; ++i) {
        int ntg = wv + 4 * i;
        if (ntg < 16) {
            int n = ntg * 16 + ln;
            float b = sb1[n];
#pragma unroll
            for (int mt = 0; mt < 2; ++mt)
#pragma unroll
                for (int r = 0; r < 4; ++r) {
                    int m = mt * 16 + q * 4 + r;
                    float z = selacc[mt][i][r] + b;
                    float e = z > 0.f ? z : (expf(z) - 1.f);
                    ys16[m * 264 + n] = (_Float16)e;
                }
        } else {
            int j = (ntg - 16) * 16 + ln;
            float b = ssb[j];
#pragma unroll
            for (int mt = 0; mt < 2; ++mt)
#pragma unroll
                for (int r = 0; r < 4; ++r) {
                    int m = mt * 16 + q * 4 + r;
                    sres_t[j * 32 + m] = selacc[mt][i][r] + b;
                }
        }
    }
    // stage sw2t (16 KB)
#pragma unroll
    for (int i = 0; i < 4; ++i) {
        int s = t + i * 256;
        GLD_LDS(sw2t + s * 8, sw2s + s * 8);
    }
    __syncthreads();
    // fc2 via MFMA: wave wv -> (mt = wv>>1, ntile = wv&1)
    float4v p;
#pragma unroll
    for (int r = 0; r < 4; ++r) p[r] = 0.f;
    {
        int mt = wv >> 1, ntile = wv & 1;
        for (int ks = 0; ks < 8; ++ks) {
            half8 af = *(const half8*)&ys16[(mt * 16 + ln) * 264 + ks * 32 + q * 8];
            half8 bf8 = *(const half8*)&sw2s[(ntile * 16 + ln) * 256 + ks * 32 + q * 8];
            p = __builtin_amdgcn_mfma_f32_16x16x32_f16(af, bf8, p, 0, 0, 0);
        }
        int j = ntile * 16 + ln;
        float b = sb2[j];
#pragma unroll
        for (int r = 0; r < 4; ++r) {
            int m = mt * 16 + q * 4 + r;
            tv_t[j * 32 + m] = p[r] + b;
        }
    }
    __syncthreads();
    // GLU: thread (m = t&31, jg = t>>5) handles j = jg*4..+3
    {
        int m = t & 31, jg = t >> 5;
#pragma unroll
        for (int jj = 0; jj < 4; ++jj) {
            int j = jg * 4 + jj;
            float g = sbg[j], u = sbf[j];
            for (int i = 0; i < 32; ++i) {
                float tvv = tv_t[i * 32 + m];
                g += tvv * swg[i * 32 + j];
                u += tvv * swf[i * 32 + j];
            }
            float sig = 1.f / (1.f + expf(-g));
            sres_t[j * 32 + m] = sres_t[j * 32 + m] + sig * u;
        }
    }
    __syncthreads();
    // LN + softmax per token (serial-32 per thread, t<32)
    if (t < 32) {
        float a = 0.f, b = 0.f;
        for (int j = 0; j < 32; ++j) { float v = sres_t[j * 32 + t]; a += v; b += v * v; }
        float mean = a * (1.f / 32.f);
        float var = b * (1.f / 32.f) - mean * mean;
        float rs = rsqrtf(var + 1e-5f);
        float mx = -1e30f;
        for (int j = 0; j < 32; ++j) {
            float v = (sres_t[j * 32 + t] - mean) * rs * sgam[j] + sbet[j];
            sres_t[j * 32 + t] = v;
            mx = fmaxf(mx, v);
        }
        float s = 0.f;
        for (int j = 0; j < 32; ++j) s += expf(sres_t[j * 32 + t] - mx);
        float inv = 1.f / s;
        for (int j = 0; j < 32; ++j)
            w_lds[t * 32 + j] = expf(sres_t[j * 32 + t] - mx) * inv;
    }
    __syncthreads();
#pragma unroll
    for (int i = 0; i < 4; ++i) {
        int idx = t + i * 256;
        wout[(size_t)m0 * 32 + idx] = w_lds[idx];
    }
}

// ---------------------------------------------------------------------------
// PASS 2: recompute stacked_f per f and accumulate out += w[:,f] * stacked_f
// ---------------------------------------------------------------------------
__global__ __launch_bounds__(256) void pass2_kernel(
    const float* __restrict__ x, const float* __restrict__ w1, const float* __restrict__ b1,
    const float* __restrict__ b2, const float* __restrict__ bg, const float* __restrict__ bfv_,
    const float* __restrict__ gamma, const float* __restrict__ beta,
    const float* __restrict__ wsk, const float* __restrict__ bsk,
    const _Float16* __restrict__ w2t, const _Float16* __restrict__ wgt,
    const _Float16* __restrict__ wft, const float* __restrict__ wfin,
    float* __restrict__ out)
{
    __shared__ __align__(16) char smem[57088];
    _Float16* As = (_Float16*)smem;                    // 32x264 fp16
    _Float16* Bs = (_Float16*)(smem + 16896);          // 256x64 fp16 [.. 49664)
    float* xs_t  = (float*)(smem + 49664);             // 32x32 [.. 53760)
    float* red   = (float*)(smem + 53760);             // 256 f32
    float* mv    = (float*)(smem + 54784);             // 64 f32
    _Float16* wls = (_Float16*)(smem + 55040);         // [m][f] 32x32 fp16 [.. 57088)

    const int m0 = blockIdx.x * 32;
    const int t = threadIdx.x;
    const int wv = t >> 6, ln = t & 15, q = (t & 63) >> 4;

#pragma unroll
    for (int i = 0; i < 4; ++i) {
        int idx = t + i * 256;
        xs_t[(idx & 31) * 32 + (idx >> 5)] = x[(size_t)m0 * F + idx];
        wls[idx] = (_Float16)wfin[(size_t)m0 * 32 + idx];
    }

    float4v oacc[2][4];
#pragma unroll
    for (int mt = 0; mt < 2; ++mt)
#pragma unroll
        for (int nt = 0; nt < 4; ++nt)
#pragma unroll
            for (int r = 0; r < 4; ++r) oacc[mt][nt][r] = 0.f;
    __syncthreads();

    float yv[2][4][4];
    for (int f = 0; f < F; ++f) {
        grn_core(f, w1, b1, b2, bg, bfv_, gamma, beta, wsk, bsk,
                 w2t, wgt, wft, As, Bs, xs_t, red, mv, t, wv, ln, q, yv);
#pragma unroll
        for (int mt = 0; mt < 2; ++mt)
#pragma unroll
            for (int r = 0; r < 4; ++r) {
                int m = mt * 16 + q * 4 + r;
                float wf16 = (float)wls[m * 32 + f];
#pragma unroll
                for (int nt = 0; nt < 4; ++nt)
                    oacc[mt][nt][r] += wf16 * yv[mt][nt][r];
            }
    }
#pragma unroll
    for (int mt = 0; mt < 2; ++mt)
#pragma unroll
        for (int nt = 0; nt < 4; ++nt) {
            int n = wv * 64 + nt * 16 + ln;
#pragma unroll
            for (int r = 0; r < 4; ++r) {
                int m = mt * 16 + q * 4 + r;
                out[(size_t)(m0 + m) * H + n] = oacc[mt][nt][r];
            }
        }
}

// ---------------------------------------------------------------------------
extern "C" void kernel_launch(void* const* d_in, const int* in_sizes, int n_in,
                              void* d_out, int out_size, void* d_ws, size_t ws_size,
                              hipStream_t stream)
{
    (void)in_sizes; (void)n_in; (void)out_size; (void)ws_size;
    const float* x    = (const float*)d_in[0];
    const float* w1   = (const float*)d_in[1];
    const float* b1   = (const float*)d_in[2];
    const float* w2   = (const float*)d_in[3];
    const float* b2   = (const float*)d_in[4];
    const float* wg   = (const float*)d_in[5];
    const float* bg   = (const float*)d_in[6];
    const float* wf   = (const float*)d_in[7];
    const float* bfp  = (const float*)d_in[8];
    const float* gamma= (const float*)d_in[9];
    const float* beta = (const float*)d_in[10];
    const float* wsk  = (const float*)d_in[11];
    const float* bsk  = (const float*)d_in[12];
    const float* sw1  = (const float*)d_in[13];
    const float* sb1  = (const float*)d_in[14];
    const float* sw2  = (const float*)d_in[15];
    const float* sb2  = (const float*)d_in[16];
    const float* swg  = (const float*)d_in[17];
    const float* sbg  = (const float*)d_in[18];
    const float* swf  = (const float*)d_in[19];
    const float* sbf  = (const float*)d_in[20];
    const float* sgam = (const float*)d_in[21];
    const float* sbet = (const float*)d_in[22];
    const float* ssw  = (const float*)d_in[23];
    const float* ssb  = (const float*)d_in[24];

    char* ws = (char*)d_ws;
    _Float16* wt   = (_Float16*)ws;                     // 3 x 2M fp16 = 12 MiB
    _Float16* wcat = (_Float16*)(ws + 12582912);        // 288x8192 fp16 = 4.5 MiB
    _Float16* sw2t = (_Float16*)(ws + 17301504);        // 32x256 fp16
    float* wbuf    = (float*)(ws + 17317888);           // 16384x32 f32 = 2 MiB
    float* out     = (float*)d_out;

    hipLaunchKernelGGL(transpose_w_kernel, dim3(1536), dim3(256), 0, stream, w2, wg, wf, wt);
    hipLaunchKernelGGL(transpose_s_kernel, dim3(641), dim3(256), 0, stream, sw1, ssw, sw2, wcat, sw2t);
    hipLaunchKernelGGL(pass1_kernel, dim3(512), dim3(256), 0, stream,
                       x, w1, b1, b2, bg, bfp, gamma, beta, wsk, bsk,
                       wt, wt + 2097152, wt + 2 * 2097152, wcat, sw2t,
                       sb1, ssb, sb2, swg, sbg, swf, sbf, sgam, sbet, wbuf);
    hipLaunchKernelGGL(pass2_kernel, dim3(512), dim3(256), 0, stream,
                       x, w1, b1, b2, bg, bfp, gamma, beta, wsk, bsk,
                       wt, wt + 2097152, wt + 2 * 2097152, wbuf, out);
}

// Round 6
// 2993.144 us; speedup vs baseline: 1.1763x; 1.1763x over previous
//
#include <hip/hip_runtime.h>
#include <hip/hip_bf16.h>
#include <hip/hip_fp16.h>

#define BT 16384
#define F 32
#define H 256
#define FH 8192

typedef _Float16 half8 __attribute__((ext_vector_type(8)));
typedef float float4v __attribute__((ext_vector_type(4)));

#define GLD_LDS(gsrc, ldst) \
    __builtin_amdgcn_global_load_lds( \
        (const __attribute__((address_space(1))) void*)(gsrc), \
        (__attribute__((address_space(3))) void*)(ldst), 16, 0, 0)

// ---------------------------------------------------------------------------
// Prep: transpose w2/wg/wf (F,H_contr,H_out) fp32 -> [f][n_out][h_contr] fp16
// ---------------------------------------------------------------------------
__global__ __launch_bounds__(256) void transpose_w_kernel(
    const float* __restrict__ w2, const float* __restrict__ wg,
    const float* __restrict__ wf, _Float16* __restrict__ wt)
{
    __shared__ float tile[64][65];
    int bid = blockIdx.x;
    int tens = bid >> 9, rem = bid & 511;
    int f = rem >> 4, tl = rem & 15;
    int hb = (tl >> 2) * 64, nb = (tl & 3) * 64;
    const float* src = (tens == 0 ? w2 : (tens == 1 ? wg : wf)) + f * 65536;
    _Float16* dst = wt + (size_t)tens * 2097152 + f * 65536;
    int lane = threadIdx.x & 63, w = threadIdx.x >> 6;
    for (int i = 0; i < 16; ++i) {
        int r = i * 4 + w;
        tile[r][lane] = src[(hb + r) * 256 + nb + lane];
    }
    __syncthreads();
    for (int i = 0; i < 16; ++i) {
        int c = i * 4 + w;
        dst[(nb + c) * 256 + hb + lane] = (_Float16)tile[lane][c];
    }
}

// ---------------------------------------------------------------------------
// Prep: Wcat[n][k] fp16, n<256 from sw1 (8192,256), n in [256,288) from ssw
// ---------------------------------------------------------------------------
__global__ __launch_bounds__(256) void transpose_s_kernel(
    const float* __restrict__ sw1, const float* __restrict__ ssw,
    _Float16* __restrict__ wcat)
{
    __shared__ float tile[64][65];
    int bid = blockIdx.x;
    int lane = threadIdx.x & 63, w = threadIdx.x >> 6;
    int t = threadIdx.x;
    if (bid < 512) {
        int k0 = (bid >> 2) * 64, n0 = (bid & 3) * 64;
        for (int i = 0; i < 16; ++i) {
            int r = i * 4 + w;
            tile[r][lane] = sw1[(size_t)(k0 + r) * 256 + n0 + lane];
        }
        __syncthreads();
        for (int i = 0; i < 16; ++i) {
            int c = i * 4 + w;
            wcat[(size_t)(n0 + c) * FH + k0 + lane] = (_Float16)tile[lane][c];
        }
    } else {
        int k0 = (bid - 512) * 64;
        for (int i = 0; i < 8; ++i) {
            int idx = t + i * 256;
            int r = idx >> 5, cc = idx & 31;
            tile[r][cc] = ssw[(size_t)(k0 + r) * 32 + cc];
        }
        __syncthreads();
        for (int i = 0; i < 8; ++i) {
            int idx = t + i * 256;
            int c = idx >> 6, rr = idx & 63;
            wcat[(size_t)(256 + c) * FH + k0 + rr] = (_Float16)tile[rr][c];
        }
    }
}

// ---------------------------------------------------------------------------
// Init: acc[tok][288] = biases; out chunk = 0.  4096 tokens per chunk.
// ---------------------------------------------------------------------------
__global__ __launch_bounds__(256) void init_kernel(
    float* __restrict__ acc, float* __restrict__ outC,
    const float* __restrict__ sb1, const float* __restrict__ ssb)
{
    int b = blockIdx.x, t = threadIdx.x;
    for (int tk = 0; tk < 8; ++tk) {
        int tok = b * 8 + tk;
        for (int n = t; n < 288; n += 256)
            acc[(size_t)tok * 288 + n] = (n < 256) ? sb1[n] : ssb[n - 256];
        outC[(size_t)tok * 256 + t] = 0.f;
    }
}

// ---------------------------------------------------------------------------
// M=64 GEMM stage (K=256, N=256): global_load_lds + XOR swizzle (R3-verified).
// ---------------------------------------------------------------------------
__device__ __forceinline__ void gemm_stage64(
    const _Float16* __restrict__ Bsrc, const _Float16* As, _Float16* Bs,
    int t, int wv, int ln, int q, float4v acc[4][4])
{
    for (int kc = 0; kc < 4; ++kc) {
        __syncthreads();
#pragma unroll
        for (int it = 0; it < 8; ++it) {
            int s = it * 256 + t;
            int n = s >> 3;
            int c = (s & 7) ^ (n & 7);
            GLD_LDS(Bsrc + n * 256 + kc * 64 + c * 8, Bs + s * 8);
        }
        __syncthreads();
        for (int ks = 0; ks < 2; ++ks) {
            half8 a[4];
#pragma unroll
            for (int mt = 0; mt < 4; ++mt)
                a[mt] = *(const half8*)&As[(mt * 16 + ln) * 264 + kc * 64 + ks * 32 + q * 8];
#pragma unroll
            for (int nt = 0; nt < 4; ++nt) {
                int n = wv * 64 + nt * 16 + ln;
                int cp = (ks * 4 + q) ^ (n & 7);
                half8 b8 = *(const half8*)&Bs[n * 64 + cp * 8];
#pragma unroll
                for (int mt = 0; mt < 4; ++mt)
                    acc[mt][nt] = __builtin_amdgcn_mfma_f32_16x16x32_f16(a[mt], b8, acc[mt][nt], 0, 0, 0);
            }
        }
    }
}

// ---------------------------------------------------------------------------
// M=64 GRN core for feature f: 3 GEMMs + GLU + residual + LayerNorm.
// Returns yv[mt][nt] C-layout: m = mt*16+q*4+r, n = wv*64+nt*16+ln.
// ---------------------------------------------------------------------------
__device__ __forceinline__ void grn_core64(
    int f, int m0g, const float* __restrict__ x,
    const float* __restrict__ w1, const float* __restrict__ b1,
    const float* __restrict__ b2, const float* __restrict__ bg,
    const float* __restrict__ bfv_, const float* __restrict__ gamma,
    const float* __restrict__ beta, const float* __restrict__ wsk,
    const float* __restrict__ bsk,
    const _Float16* __restrict__ w2t, const _Float16* __restrict__ wgt,
    const _Float16* __restrict__ wft,
    _Float16* As, _Float16* Bs, float* xs, float* red, float* mv,
    int t, int wv, int ln, int q, float4v yv[4][4])
{
    if (t < 64) xs[t] = x[(size_t)(m0g + t) * F + f];
    __syncthreads();
    {
        float w1v = w1[f * H + t];
        float b1v = b1[f * H + t];
#pragma unroll 4
        for (int i = 0; i < 64; ++i) {
            float z = xs[i] * w1v + b1v;
            As[i * 264 + t] = (_Float16)(z > 0.f ? z : (expf(z) - 1.f));
        }
    }
    float4v acc1[4][4];
#pragma unroll
    for (int mt = 0; mt < 4; ++mt)
#pragma unroll
        for (int nt = 0; nt < 4; ++nt)
#pragma unroll
            for (int r = 0; r < 4; ++r) acc1[mt][nt][r] = 0.f;
    gemm_stage64(w2t + (size_t)f * 65536, As, Bs, t, wv, ln, q, acc1);
    __syncthreads();
    {
        const float* b2f = b2 + f * H;
#pragma unroll
        for (int mt = 0; mt < 4; ++mt)
#pragma unroll
            for (int nt = 0; nt < 4; ++nt) {
                int n = wv * 64 + nt * 16 + ln;
                float b2v = b2f[n];
#pragma unroll
                for (int r = 0; r < 4; ++r) {
                    int m = mt * 16 + q * 4 + r;
                    As[m * 264 + n] = (_Float16)(acc1[mt][nt][r] + b2v);
                }
            }
    }
    float4v aG[4][4], aF[4][4];
#pragma unroll
    for (int mt = 0; mt < 4; ++mt)
#pragma unroll
        for (int nt = 0; nt < 4; ++nt)
#pragma unroll
            for (int r = 0; r < 4; ++r) { aG[mt][nt][r] = 0.f; aF[mt][nt][r] = 0.f; }
    gemm_stage64(wgt + (size_t)f * 65536, As, Bs, t, wv, ln, q, aG);
    gemm_stage64(wft + (size_t)f * 65536, As, Bs, t, wv, ln, q, aF);
    __syncthreads();
    // GLU + residual
    {
        const float* bgf = bg + f * H;
        const float* bff = bfv_ + f * H;
        const float* wsf = wsk + f * H;
        const float* bsf = bsk + f * H;
#pragma unroll
        for (int mt = 0; mt < 4; ++mt)
#pragma unroll
            for (int nt = 0; nt < 4; ++nt) {
                int n = wv * 64 + nt * 16 + ln;
                float bgv = bgf[n], bfv = bff[n], wsv = wsf[n], bsv = bsf[n];
#pragma unroll
                for (int r = 0; r < 4; ++r) {
                    int m = mt * 16 + q * 4 + r;
                    float cg = aG[mt][nt][r] + bgv;
                    float cf = aF[mt][nt][r] + bfv;
                    float sig = 1.f / (1.f + expf(-cg));
                    yv[mt][nt][r] = sig * cf + xs[m] * wsv + bsv;
                }
            }
    }
    // LayerNorm: per-row sums via 16-lane butterfly -> red[m*4+wv]
#pragma unroll
    for (int mt = 0; mt < 4; ++mt)
#pragma unroll
        for (int r = 0; r < 4; ++r) {
            float s1 = 0.f, s2 = 0.f;
#pragma unroll
            for (int nt = 0; nt < 4; ++nt) {
                float v = yv[mt][nt][r];
                s1 += v; s2 += v * v;
            }
#pragma unroll
            for (int off = 1; off < 16; off <<= 1) {
                s1 += __shfl_xor(s1, off, 16);
                s2 += __shfl_xor(s2, off, 16);
            }
            if (ln == 0) {
                int m = mt * 16 + q * 4 + r;
                red[m * 4 + wv] = s1;
                red[256 + m * 4 + wv] = s2;
            }
        }
    __syncthreads();
    if (t < 64) {
        float a = red[t * 4] + red[t * 4 + 1] + red[t * 4 + 2] + red[t * 4 + 3];
        float b = red[256 + t * 4] + red[256 + t * 4 + 1] + red[256 + t * 4 + 2] + red[256 + t * 4 + 3];
        float mean = a * (1.f / 256.f);
        float var = b * (1.f / 256.f) - mean * mean;
        mv[t] = mean;
        mv[64 + t] = rsqrtf(var + 1e-5f);
    }
    __syncthreads();
    {
        const float* gf = gamma + f * H;
        const float* bf2 = beta + f * H;
#pragma unroll
        for (int mt = 0; mt < 4; ++mt)
#pragma unroll
            for (int nt = 0; nt < 4; ++nt) {
                int n = wv * 64 + nt * 16 + ln;
                float gv = gf[n], bv = bf2[n];
#pragma unroll
                for (int r = 0; r < 4; ++r) {
                    int m = mt * 16 + q * 4 + r;
                    yv[mt][nt][r] = (yv[mt][nt][r] - mv[m]) * mv[64 + m] * gv + bv;
                }
            }
    }
}

// ---------------------------------------------------------------------------
// KERNEL A: grid (64 m-tiles, 32 f). GRN core -> y_f -> sel partial
// P = y_f @ wcat_f^T (64x288, K=256) -> atomic add into acc (bias-inited).
// ---------------------------------------------------------------------------
__global__ __launch_bounds__(256, 2) void kernelA(
    const float* __restrict__ x, const float* __restrict__ w1, const float* __restrict__ b1,
    const float* __restrict__ b2, const float* __restrict__ bg, const float* __restrict__ bfv_,
    const float* __restrict__ gamma, const float* __restrict__ beta,
    const float* __restrict__ wsk, const float* __restrict__ bsk,
    const _Float16* __restrict__ w2t, const _Float16* __restrict__ wgt,
    const _Float16* __restrict__ wft, const _Float16* __restrict__ wcat,
    float* __restrict__ acc, int tok_base)
{
    __shared__ __align__(16) char smem[73472];
    _Float16* As = (_Float16*)smem;                    // 64x264 fp16 [0,33792)
    _Float16* Bs = (_Float16*)(smem + 33792);          // up to 288x64 fp16 [..70656)
    float* xs    = (float*)(smem + 70656);             // 64
    float* red   = (float*)(smem + 70912);             // 512
    float* mv    = (float*)(smem + 72960);             // 128

    const int f = blockIdx.y;
    const int m0 = blockIdx.x * 64;                    // chunk-local
    const int t = threadIdx.x;
    const int wv = t >> 6, ln = t & 15, q = (t & 63) >> 4;
    const int NT = (wv < 2) ? 5 : 4;

    float4v yv[4][4];
    grn_core64(f, tok_base + m0, x, w1, b1, b2, bg, bfv_, gamma, beta, wsk, bsk,
               w2t, wgt, wft, As, Bs, xs, red, mv, t, wv, ln, q, yv);

    // write y_f into As (A-layout)
#pragma unroll
    for (int mt = 0; mt < 4; ++mt)
#pragma unroll
        for (int nt = 0; nt < 4; ++nt) {
            int n = wv * 64 + nt * 16 + ln;
#pragma unroll
            for (int r = 0; r < 4; ++r) {
                int m = mt * 16 + q * 4 + r;
                As[m * 264 + n] = (_Float16)yv[mt][nt][r];
            }
        }

    // sel GEMM: P = y_f (64x256) @ wcat_f^T (256x288)
    float4v selacc[4][5];
#pragma unroll
    for (int mt = 0; mt < 4; ++mt)
#pragma unroll
        for (int i = 0; i < 5; ++i)
#pragma unroll
            for (int r = 0; r < 4; ++r) selacc[mt][i][r] = 0.f;

    for (int kc = 0; kc < 4; ++kc) {
        __syncthreads();
#pragma unroll
        for (int i = 0; i < 9; ++i) {
            int s = t + i * 256;
            int nb = s >> 3;
            int cb = (s & 7) ^ (nb & 7);
            GLD_LDS(wcat + (size_t)nb * FH + f * 256 + kc * 64 + cb * 8, Bs + s * 8);
        }
        __syncthreads();
        for (int ks = 0; ks < 2; ++ks) {
            half8 a[4];
#pragma unroll
            for (int mt = 0; mt < 4; ++mt)
                a[mt] = *(const half8*)&As[(mt * 16 + ln) * 264 + kc * 64 + ks * 32 + q * 8];
            for (int i = 0; i < NT; ++i) {
                int row = (wv + 4 * i) * 16 + ln;
                int cp = (ks * 4 + q) ^ (row & 7);
                half8 b8 = *(const half8*)&Bs[row * 64 + cp * 8];
#pragma unroll
                for (int mt = 0; mt < 4; ++mt)
                    selacc[mt][i] = __builtin_amdgcn_mfma_f32_16x16x32_f16(a[mt], b8, selacc[mt][i], 0, 0, 0);
            }
        }
    }
    for (int i = 0; i < NT; ++i) {
        int n = (wv + 4 * i) * 16 + ln;
#pragma unroll
        for (int mt = 0; mt < 4; ++mt)
#pragma unroll
            for (int r = 0; r < 4; ++r) {
                int m = mt * 16 + q * 4 + r;
                unsafeAtomicAdd(&acc[(size_t)(m0 + m) * 288 + n], selacc[mt][i][r]);
            }
    }
}

// ---------------------------------------------------------------------------
// KERNEL B: tail. acc -> elu -> fc2(256->32) -> GLU -> LN -> softmax -> wbuf.
// Block = 8 tokens (32 lanes each), chunk-local.
// ---------------------------------------------------------------------------
__global__ __launch_bounds__(256) void kernelB(
    const float* __restrict__ acc,
    const float* __restrict__ sw2, const float* __restrict__ sb2,
    const float* __restrict__ swg, const float* __restrict__ sbg,
    const float* __restrict__ swf, const float* __restrict__ sbf,
    const float* __restrict__ sgam, const float* __restrict__ sbet,
    float* __restrict__ wbuf)
{
    __shared__ float sw2s[256 * 32];
    __shared__ float swgs[1024], swfs[1024];
    __shared__ float shv[8][257];
    const int t = threadIdx.x;
    for (int i = 0; i < 32; ++i) sw2s[t + i * 256] = sw2[t + i * 256];
    for (int i = 0; i < 4; ++i) {
        swgs[t + i * 256] = swg[t + i * 256];
        swfs[t + i * 256] = swf[t + i * 256];
    }
    for (int i = 0; i < 8; ++i) {
        int idx = t + i * 256;
        int gg = idx >> 8, col = idx & 255;
        float z = acc[(size_t)(blockIdx.x * 8 + gg) * 288 + col];
        shv[gg][col] = z > 0.f ? z : (expf(z) - 1.f);
    }
    __syncthreads();
    const int g = t >> 5;
    const int j = t & 31;
    const int token = blockIdx.x * 8 + g;
    float p = sb2[j];
    for (int k = 0; k < 256; ++k) p += shv[g][k] * sw2s[k * 32 + j];
    float gacc = sbg[j], uacc = sbf[j];
#pragma unroll 8
    for (int i = 0; i < 32; ++i) {
        float tv = __shfl(p, i, 32);
        gacc += tv * swgs[i * 32 + j];
        uacc += tv * swfs[i * 32 + j];
    }
    float sig = 1.f / (1.f + expf(-gacc));
    float sv = acc[(size_t)token * 288 + 256 + j] + sig * uacc;
    float s1 = sv, s2 = sv * sv;
    for (int off = 16; off; off >>= 1) {
        s1 += __shfl_xor(s1, off, 32);
        s2 += __shfl_xor(s2, off, 32);
    }
    float mean = s1 * (1.f / 32.f);
    float var = s2 * (1.f / 32.f) - mean * mean;
    float v = (sv - mean) * rsqrtf(var + 1e-5f) * sgam[j] + sbet[j];
    float mx = v;
    for (int off = 16; off; off >>= 1) mx = fmaxf(mx, __shfl_xor(mx, off, 32));
    float e = expf(v - mx);
    float ssum = e;
    for (int off = 16; off; off >>= 1) ssum += __shfl_xor(ssum, off, 32);
    wbuf[(size_t)token * 32 + j] = e / ssum;
}

// ---------------------------------------------------------------------------
// KERNEL C: grid (64 m-tiles, 32 f). Recompute y_f; atomic out += w_f * y_f.
// ---------------------------------------------------------------------------
__global__ __launch_bounds__(256, 2) void kernelC(
    const float* __restrict__ x, const float* __restrict__ w1, const float* __restrict__ b1,
    const float* __restrict__ b2, const float* __restrict__ bg, const float* __restrict__ bfv_,
    const float* __restrict__ gamma, const float* __restrict__ beta,
    const float* __restrict__ wsk, const float* __restrict__ bsk,
    const _Float16* __restrict__ w2t, const _Float16* __restrict__ wgt,
    const _Float16* __restrict__ wft, const float* __restrict__ wbuf,
    float* __restrict__ out, int tok_base)
{
    __shared__ __align__(16) char smem[69888];
    _Float16* As = (_Float16*)smem;                    // 64x264 fp16 [0,33792)
    _Float16* Bs = (_Float16*)(smem + 33792);          // 256x64 fp16 [..66560)
    float* xs    = (float*)(smem + 66560);             // 64
    float* red   = (float*)(smem + 66816);             // 512
    float* mv    = (float*)(smem + 68864);             // 128
    float* wls   = (float*)(smem + 69376);             // 64

    const int f = blockIdx.y;
    const int m0 = blockIdx.x * 64;                    // chunk-local
    const int t = threadIdx.x;
    const int wv = t >> 6, ln = t & 15, q = (t & 63) >> 4;

    if (t < 64) wls[t] = wbuf[(size_t)(m0 + t) * 32 + f];

    float4v yv[4][4];
    grn_core64(f, tok_base + m0, x, w1, b1, b2, bg, bfv_, gamma, beta, wsk, bsk,
               w2t, wgt, wft, As, Bs, xs, red, mv, t, wv, ln, q, yv);

#pragma unroll
    for (int mt = 0; mt < 4; ++mt)
#pragma unroll
        for (int r = 0; r < 4; ++r) {
            int m = mt * 16 + q * 4 + r;
            float wfv = wls[m];
#pragma unroll
            for (int nt = 0; nt < 4; ++nt) {
                int n = wv * 64 + nt * 16 + ln;
                unsafeAtomicAdd(&out[(size_t)(tok_base + m0 + m) * H + n], wfv * yv[mt][nt][r]);
            }
        }
}

// ---------------------------------------------------------------------------
extern "C" void kernel_launch(void* const* d_in, const int* in_sizes, int n_in,
                              void* d_out, int out_size, void* d_ws, size_t ws_size,
                              hipStream_t stream)
{
    (void)in_sizes; (void)n_in; (void)out_size; (void)ws_size;
    const float* x    = (const float*)d_in[0];
    const float* w1   = (const float*)d_in[1];
    const float* b1   = (const float*)d_in[2];
    const float* w2   = (const float*)d_in[3];
    const float* b2   = (const float*)d_in[4];
    const float* wg   = (const float*)d_in[5];
    const float* bg   = (const float*)d_in[6];
    const float* wf   = (const float*)d_in[7];
    const float* bfp  = (const float*)d_in[8];
    const float* gamma= (const float*)d_in[9];
    const float* beta = (const float*)d_in[10];
    const float* wsk  = (const float*)d_in[11];
    const float* bsk  = (const float*)d_in[12];
    const float* sw1  = (const float*)d_in[13];
    const float* sb1  = (const float*)d_in[14];
    const float* sw2  = (const float*)d_in[15];
    const float* sb2  = (const float*)d_in[16];
    const float* swg  = (const float*)d_in[17];
    const float* sbg  = (const float*)d_in[18];
    const float* swf  = (const float*)d_in[19];
    const float* sbf  = (const float*)d_in[20];
    const float* sgam = (const float*)d_in[21];
    const float* sbet = (const float*)d_in[22];
    const float* ssw  = (const float*)d_in[23];
    const float* ssb  = (const float*)d_in[24];

    char* ws = (char*)d_ws;
    _Float16* wt   = (_Float16*)ws;                     // 3 x 2M fp16 = 12.58 MB
    _Float16* wcat = (_Float16*)(ws + 12582912);        // 288x8192 fp16 = 4.72 MB
    float* acc     = (float*)(ws + 17301504);           // 4096x288 f32 = 4.72 MB
    float* wbuf    = (float*)(ws + 22020096);           // 4096x32 f32 = 0.52 MB
    float* out     = (float*)d_out;
    // total ws use: ~22.6 MB (ws_size known >= 26.3 MB)

    hipLaunchKernelGGL(transpose_w_kernel, dim3(1536), dim3(256), 0, stream, w2, wg, wf, wt);
    hipLaunchKernelGGL(transpose_s_kernel, dim3(640), dim3(256), 0, stream, sw1, ssw, wcat);
    for (int c = 0; c < 4; ++c) {
        int tb = c * 4096;
        hipLaunchKernelGGL(init_kernel, dim3(512), dim3(256), 0, stream,
                           acc, out + (size_t)tb * 256, sb1, ssb);
        hipLaunchKernelGGL(kernelA, dim3(64, 32), dim3(256), 0, stream,
                           x, w1, b1, b2, bg, bfp, gamma, beta, wsk, bsk,
                           wt, wt + 2097152, wt + 2 * 2097152, wcat, acc, tb);
        hipLaunchKernelGGL(kernelB, dim3(512), dim3(256), 0, stream,
                           acc, sw2, sb2, swg, sbg, swf, sbf, sgam, sbet, wbuf);
        hipLaunchKernelGGL(kernelC, dim3(64, 32), dim3(256), 0, stream,
                           x, w1, b1, b2, bg, bfp, gamma, beta, wsk, bsk,
                           wt, wt + 2097152, wt + 2 * 2097152, wbuf, out, tb);
    }
}